// Round 12
// baseline (802.131 us; speedup 1.0000x reference)
//
#include <hip/hip_runtime.h>
#include <hip/hip_bf16.h>

#define B_ 4
#define N_ 2048
#define D_ 1024
#define H_ 16
#define HD_ 64
#define MTOT (B_*N_)   // 8192
#define CH_ 16         // scan chunk size
#define NCH_ (N_/CH_)  // 128

typedef __attribute__((ext_vector_type(8))) short short8v;
typedef __attribute__((ext_vector_type(4))) float f32x4;

// ---------------- cast x -> bf16 (vectorized) ----------------
__global__ void k_cast_bf16(const float* __restrict__ in, __hip_bfloat16* __restrict__ out, int n4){
  int i = blockIdx.x*256 + threadIdx.x;
  if (i >= n4) return;
  float4 vv = ((const float4*)in)[i];
  __hip_bfloat16 b0 = __float2bfloat16(vv.x), b1 = __float2bfloat16(vv.y),
                 b2 = __float2bfloat16(vv.z), b3 = __float2bfloat16(vv.w);
  ushort4 o;
  o.x = *(const unsigned short*)&b0; o.y = *(const unsigned short*)&b1;
  o.z = *(const unsigned short*)&b2; o.w = *(const unsigned short*)&b3;
  ((ushort4*)out)[i] = o;
}

// ---------------- transpose + cast: out[c][r] = in[r][c] ----------------
__global__ void k_transpose_cast(const float* __restrict__ in, __hip_bfloat16* __restrict__ out,
                                 int R, int C){
  __shared__ float tile[64][65];
  int r0 = blockIdx.y*64, c0 = blockIdx.x*64;
  int tid = threadIdx.x;
  #pragma unroll
  for (int i=0;i<16;i++){ int idx = tid + i*256; int rr = idx>>6, cc = idx&63;
    tile[rr][cc] = in[(size_t)(r0+rr)*C + (c0+cc)]; }
  __syncthreads();
  #pragma unroll
  for (int i=0;i<16;i++){ int idx = tid + i*256; int rr = idx>>6, cc = idx&63;
    out[(size_t)(c0+rr)*R + (r0+cc)] = __float2bfloat16(tile[cc][rr]); }
}

// ---------------- pack gate/lr weights: WgL[128][1024] = [Wg1^T ; Wlr^T ; 0] ----------------
__global__ void k_prep_wgl(const float* __restrict__ Wg1, const float* __restrict__ Wlr,
                           __hip_bfloat16* __restrict__ WgL){
  int idx = blockIdx.x*256 + threadIdx.x;   // 0..131071
  int r = idx >> 10, d = idx & 1023;
  float v = 0.f;
  if (r < 64) v = Wg1[(size_t)d*64 + r];
  else if (r < 80) v = Wlr[(size_t)d*16 + (r-64)];
  WgL[idx] = __float2bfloat16(v);
}

// ---------------- post: proj[8192][128] -> t1 bf16 (cols 0-63), lr = 0.01*sigmoid (cols 64-79) ----
__global__ void k_post_gl(const float* __restrict__ proj, __hip_bfloat16* __restrict__ t1,
                          float* __restrict__ lrout){
  int m = blockIdx.x*4 + (threadIdx.x>>6);
  int e = threadIdx.x & 63;
  float val = proj[(size_t)m*128 + e];
  t1[(size_t)m*64 + e] = __float2bfloat16(val);
  if (e < 16){
    float s = proj[(size_t)m*128 + 64 + e];
    lrout[(size_t)m*16 + e] = 0.01f/(1.0f+__expf(-s));
  }
}

// ---------------- async global->LDS helper (16B per lane, dest = base + lane*16) ----------------
__device__ __forceinline__ void gl2lds16(const void* g, void* l){
  __builtin_amdgcn_global_load_lds((const __attribute__((address_space(1))) void*)g,
                                   (__attribute__((address_space(3))) void*)l, 16, 0, 0);
}

// ---------------- bf16 MFMA GEMM with global_load_lds staging ----------------
template<int ACT, int LAYOUT>
__global__ __launch_bounds__(256,2) void k_gemm_bt2(
    const __hip_bfloat16* __restrict__ A, const __hip_bfloat16* __restrict__ BT,
    float* __restrict__ C, int M, int N, int K)
{
  __shared__ short As[128*32];
  __shared__ short Bs[128*32];
  const int n0 = blockIdx.x*128, m0 = blockIdx.y*128;
  const int tid = threadIdx.x, lane = tid & 63, wid = tid >> 6;
  const int wm = wid >> 1, wn = wid & 1;
  const short* Aps = (const short*)A;
  const short* Bps = (const short*)BT;
  f32x4 acc[4][4] = {};
  const int srow = wid*32 + (lane>>2);
  const int scol = (lane&3)*8;
  const size_t aoff0 = (size_t)(m0+srow)*K + scol;
  const size_t boff0 = (size_t)(n0+srow)*K + scol;
  short* lA = As + wid*1024;
  short* lB = Bs + wid*1024;
  const int row = lane & 15, kq = (lane >> 4)*8;
  for (int kk = 0; kk < K; kk += 32) {
    __syncthreads();
    gl2lds16(Aps + aoff0 + kk,                 lA);
    gl2lds16(Aps + aoff0 + (size_t)16*K + kk,  lA + 512);
    gl2lds16(Bps + boff0 + kk,                 lB);
    gl2lds16(Bps + boff0 + (size_t)16*K + kk,  lB + 512);
    __syncthreads();
    short8v af[4], bfr[4];
    #pragma unroll
    for (int i=0;i<4;i++) af[i]  = *(const short8v*)(As + (wm*64 + i*16 + row)*32 + kq);
    #pragma unroll
    for (int j=0;j<4;j++) bfr[j] = *(const short8v*)(Bs + (wn*64 + j*16 + row)*32 + kq);
    #pragma unroll
    for (int i=0;i<4;i++)
      #pragma unroll
      for (int j=0;j<4;j++)
        acc[i][j] = __builtin_amdgcn_mfma_f32_16x16x32_bf16(af[i], bfr[j], acc[i][j], 0, 0, 0);
  }
  #pragma unroll
  for (int i=0;i<4;i++){
    #pragma unroll
    for (int j=0;j<4;j++){
      int col = n0 + wn*64 + j*16 + (lane & 15);
      #pragma unroll
      for (int qq=0; qq<4; ++qq){
        int rowg = m0 + wm*64 + i*16 + (lane>>4)*4 + qq;
        float val = acc[i][j][qq];
        if (ACT==1) val = val/(1.0f+__expf(-val));
        if (LAYOUT==0) {
          C[(size_t)rowg*N + col] = val;
        } else {
          size_t oidx = ((((size_t)(rowg>>11))*16 + (col>>6))*(size_t)N_ + (size_t)(rowg & 2047))*64
                        + (size_t)(col & 63);
          C[oidx] = val;
        }
      }
    }
  }
}

// ---------------- helpers for chunked scan ----------------
__device__ __forceinline__ unsigned short bfr16(float x){
  __hip_bfloat16 b = __float2bfloat16(x);
  return *(unsigned short*)&b;
}
__device__ __forceinline__ short8v cvt_frag(const float4 a, const float4 c){
  short8v r;
  r[0]=(short)bfr16(a.x); r[1]=(short)bfr16(a.y); r[2]=(short)bfr16(a.z); r[3]=(short)bfr16(a.w);
  r[4]=(short)bfr16(c.x); r[5]=(short)bfr16(c.y); r[6]=(short)bfr16(c.z); r[7]=(short)bfr16(c.w);
  return r;
}

// ---------------- chunked fast-weight scan v11: SINGLE WAVE per (b,h,slab) ----------------
// 256 blocks x 64 threads. No __syncthreads anywhere: phase ordering is in-wave
// program order + lgkmcnt. W master lives in frag-aligned registers (lane: e=l&15,
// d = m*32 + (l>>4)*8 + j); bf16 W-frags rebuilt in-register (no LDS mirror).
// Prefetch (k,q,v,lr of c+1) stays in flight across phase boundaries (no vmcnt drain).
__global__ __launch_bounds__(64,1) void k_scan11(
    const float* __restrict__ q, const float* __restrict__ k, const float* __restrict__ v,
    const float* __restrict__ lr, const float* __restrict__ w1i, const float* __restrict__ w3i,
    float* __restrict__ so)
{
  const int blk = blockIdx.x;            // 0..255
  const int bh  = blk >> 2;              // b*16+h
  const int sl  = blk & 3;               // 16-col e-slab
  const int b = bh >> 4, h = bh & 15;
  const int e0 = sl*16;
  const int lane = threadIdx.x;          // 0..63
  const int tA = lane & 15, g = lane >> 4;

  __shared__ __align__(16) float KW1e[256], KW3e[256];  // [e][t], swizzled 16B slots
  __shared__ __align__(16) float QW1[256], QW3[256];    // [t][e]
  __shared__ __align__(16) float GKK[256], GQK[256];    // [t][s]
  __shared__ __align__(16) float C13[512];              // [s][e][{c1,c3}]
  __shared__ __align__(16) float vS[256];               // [t][e]
  __shared__ float lrS[16];

  const float* kfb = k + (size_t)bh*N_*64;
  const float* qfb = q + (size_t)bh*N_*64;
  const float* vfb = v + (size_t)bh*N_*64;
  const float* lrp = lr + ((size_t)b*N_)*16 + h;
  float* sob = so + (((size_t)b*N_)*16 + h)*64 + e0;

  // masters: lane owns e = e0+tA, d = m*32 + g*8 + j
  float w1m[2][8], w3m[2][8];
  {
    const float* w1p = w1i + (size_t)h*HD_*HD_ + e0 + tA;
    const float* w3p = w3i + (size_t)h*HD_*HD_ + e0 + tA;
    #pragma unroll
    for (int m=0;m<2;m++)
      #pragma unroll
      for (int j=0;j<8;j++){
        const int d = m*32 + g*8 + j;
        w1m[m][j] = w1p[(size_t)d*64];
        w3m[m][j] = w3p[(size_t)d*64];
      }
  }
  short8v wb1[2], wb3[2];
  #pragma unroll
  for (int m=0;m<2;m++){
    short8v r1, r3;
    #pragma unroll
    for (int j=0;j<8;j++){ r1[j]=(short)bfr16(w1m[m][j]); r3[j]=(short)bfr16(w3m[m][j]); }
    wb1[m]=r1; wb3[m]=r3;
  }

  // prefetch chunk 0
  float4 kP[4], qP[4]; float vP[4]; float lrP = 0.f;
  {
    const float* kr = kfb + (size_t)tA*64 + g*8;
    const float* qr = qfb + (size_t)tA*64 + g*8;
    #pragma unroll
    for (int m=0;m<2;m++){
      kP[m*2]   = *(const float4*)(kr + m*32);
      kP[m*2+1] = *(const float4*)(kr + m*32 + 4);
      qP[m*2]   = *(const float4*)(qr + m*32);
      qP[m*2+1] = *(const float4*)(qr + m*32 + 4);
    }
    #pragma unroll
    for (int i=0;i<4;i++) vP[i] = vfb[(size_t)(g*4+i)*64 + e0 + tA];
    if (lane < 16) lrP = lrp[(size_t)lane*16];
  }

  #pragma unroll 1
  for (int c = 0; c < NCH_; ++c) {
    const int t0 = c*CH_;
    // ---- phase 1: stage v/lr, build frags, MFMA products, prefetch c+1 ----
    #pragma unroll
    for (int i=0;i<4;i++) vS[(g*4+i)*16 + tA] = vP[i];
    if (lane < 16) lrS[lane] = lrP;
    short8v ka0 = cvt_frag(kP[0],kP[1]), ka1 = cvt_frag(kP[2],kP[3]);
    short8v qa0 = cvt_frag(qP[0],qP[1]), qa1 = cvt_frag(qP[2],qP[3]);
    const int tn0 = ((c+1 < NCH_) ? (c+1) : c)*CH_;
    {
      const float* kr = kfb + (size_t)(tn0+tA)*64 + g*8;
      const float* qr = qfb + (size_t)(tn0+tA)*64 + g*8;
      #pragma unroll
      for (int m=0;m<2;m++){
        kP[m*2]   = *(const float4*)(kr + m*32);
        kP[m*2+1] = *(const float4*)(kr + m*32 + 4);
        qP[m*2]   = *(const float4*)(qr + m*32);
        qP[m*2+1] = *(const float4*)(qr + m*32 + 4);
      }
      #pragma unroll
      for (int i=0;i<4;i++) vP[i] = vfb[(size_t)(tn0+g*4+i)*64 + e0 + tA];
      if (lane < 16) lrP = lrp[(size_t)(tn0+lane)*16];
    }
    f32x4 aKW1={}, aKW3={}, aQW1={}, aQW3={}, aGKK={}, aGQK={};
    aKW1 = __builtin_amdgcn_mfma_f32_16x16x32_bf16(ka0, wb1[0], aKW1, 0,0,0);
    aKW1 = __builtin_amdgcn_mfma_f32_16x16x32_bf16(ka1, wb1[1], aKW1, 0,0,0);
    aKW3 = __builtin_amdgcn_mfma_f32_16x16x32_bf16(ka0, wb3[0], aKW3, 0,0,0);
    aKW3 = __builtin_amdgcn_mfma_f32_16x16x32_bf16(ka1, wb3[1], aKW3, 0,0,0);
    aQW1 = __builtin_amdgcn_mfma_f32_16x16x32_bf16(qa0, wb1[0], aQW1, 0,0,0);
    aQW1 = __builtin_amdgcn_mfma_f32_16x16x32_bf16(qa1, wb1[1], aQW1, 0,0,0);
    aQW3 = __builtin_amdgcn_mfma_f32_16x16x32_bf16(qa0, wb3[0], aQW3, 0,0,0);
    aQW3 = __builtin_amdgcn_mfma_f32_16x16x32_bf16(qa1, wb3[1], aQW3, 0,0,0);
    aGKK = __builtin_amdgcn_mfma_f32_16x16x32_bf16(ka0, ka0, aGKK, 0,0,0);
    aGKK = __builtin_amdgcn_mfma_f32_16x16x32_bf16(ka1, ka1, aGKK, 0,0,0);
    aGQK = __builtin_amdgcn_mfma_f32_16x16x32_bf16(qa0, ka0, aGQK, 0,0,0);
    aGQK = __builtin_amdgcn_mfma_f32_16x16x32_bf16(qa1, ka1, aGQK, 0,0,0);
    const int slot = (g*4) ^ (((tA>>1)&3)<<2);
    *(f32x4*)&KW1e[tA*16 + slot] = aKW1;
    *(f32x4*)&KW3e[tA*16 + slot] = aKW3;
    #pragma unroll
    for (int qq=0;qq<4;++qq){
      QW1[(g*4+qq)*16 + tA] = aQW1[qq];
      QW3[(g*4+qq)*16 + tA] = aQW3[qq];
      GKK[(g*4+qq)*16 + tA] = aGKK[qq];
      GQK[(g*4+qq)*16 + tA] = aGQK[qq];
    }
    asm volatile("s_waitcnt lgkmcnt(0)" ::: "memory");
    __builtin_amdgcn_sched_barrier(0);

    // ---- phase B: lanes<16 serial recurrence (scan8 eager core) ----
    if (lane < 16) {
      float a1[16], a3[16];
      const int swr = ((lane>>1)&3)<<2;
      #pragma unroll
      for (int i2=0;i2<4;i2++){
        f32x4 x1 = *(const f32x4*)&KW1e[lane*16 + ((i2*4) ^ swr)];
        f32x4 x3 = *(const f32x4*)&KW3e[lane*16 + ((i2*4) ^ swr)];
        a1[i2*4+0]=x1[0]; a1[i2*4+1]=x1[1]; a1[i2*4+2]=x1[2]; a1[i2*4+3]=x1[3];
        a3[i2*4+0]=x3[0]; a3[i2*4+1]=x3[1]; a3[i2*4+2]=x3[2]; a3[i2*4+3]=x3[3];
      }
      f32x4 grow[3][4];
      #pragma unroll
      for (int i2=0;i2<4;i2++){
        grow[0][i2] = *(const f32x4*)&GKK[ 0 + i2*4];
        grow[1][i2] = *(const f32x4*)&GKK[16 + i2*4];
        grow[2][i2] = *(const f32x4*)&GKK[32 + i2*4];
      }
      #pragma unroll
      for (int t = 0; t < CH_; ++t) {
        const float h1 = a1[t], h3 = a3[t];
        const float sg = 1.0f/(1.0f + __expf(-h1));
        const float s1 = h1*sg;
        const float er = fmaf(s1, h3, -vS[t*16+lane]);
        const float ds = sg*fmaf(h1, 1.0f - sg, 1.0f);
        const float lt = lrS[t];
        float2 cc; cc.x = lt*(er*h3*ds); cc.y = lt*(er*s1);
        *(float2*)&C13[(t*16+lane)*2] = cc;
        #pragma unroll
        for (int t2 = t+1; t2 < CH_; ++t2) {
          const float gg = grow[t%3][t2>>2][t2&3];
          a1[t2] = fmaf(-gg, cc.x, a1[t2]);
          a3[t2] = fmaf(-gg, cc.y, a3[t2]);
        }
        if (t + 3 < CH_) {
          #pragma unroll
          for (int i2=0;i2<4;i2++) grow[(t+3)%3][i2] = *(const f32x4*)&GKK[(t+3)*16 + i2*4];
        }
      }
    }
    asm volatile("s_waitcnt lgkmcnt(0)" ::: "memory");
    __builtin_amdgcn_sched_barrier(0);

    // ---- phase O: all 64 lanes; lane covers (ot = g*4+i, oe = tA) ----
    float c1r[16], c3r[16];
    #pragma unroll
    for (int s=0;s<CH_;++s){
      float2 cc = *(const float2*)&C13[(s*16+tA)*2];
      c1r[s]=cc.x; c3r[s]=cc.y;
    }
    #pragma unroll
    for (int i=0;i<4;++i){
      const int ot = g*4 + i;
      float o1 = QW1[ot*16+tA], o3 = QW3[ot*16+tA];
      float gq[16];
      #pragma unroll
      for (int i2=0;i2<4;i2++){
        f32x4 a = *(const f32x4*)&GQK[ot*16 + i2*4];
        gq[i2*4]=a[0]; gq[i2*4+1]=a[1]; gq[i2*4+2]=a[2]; gq[i2*4+3]=a[3];
      }
      #pragma unroll
      for (int s=0;s<CH_;++s){
        const float gg = (s <= ot) ? gq[s] : 0.0f;
        o1 = fmaf(-gg, c1r[s], o1);
        o3 = fmaf(-gg, c3r[s], o3);
      }
      sob[(size_t)(t0+ot)*(H_*HD_) + tA] = (o1/(1.0f + __expf(-o1)))*o3;
    }

    // ---- phase C: rank-16 master update (frag-aligned) + rebuild bf16 frags ----
    #pragma unroll
    for (int s=0;s<CH_;++s){
      const float* kr = kfb + (size_t)(t0+s)*64 + g*8;
      const float4 k0 = *(const float4*)(kr);
      const float4 k1 = *(const float4*)(kr+4);
      const float4 k2 = *(const float4*)(kr+32);
      const float4 k3 = *(const float4*)(kr+36);
      const float c1 = c1r[s], c3 = c3r[s];
      float kk0[8] = {k0.x,k0.y,k0.z,k0.w,k1.x,k1.y,k1.z,k1.w};
      float kk1[8] = {k2.x,k2.y,k2.z,k2.w,k3.x,k3.y,k3.z,k3.w};
      #pragma unroll
      for (int j=0;j<8;j++){
        w1m[0][j] = fmaf(-kk0[j], c1, w1m[0][j]);
        w3m[0][j] = fmaf(-kk0[j], c3, w3m[0][j]);
        w1m[1][j] = fmaf(-kk1[j], c1, w1m[1][j]);
        w3m[1][j] = fmaf(-kk1[j], c3, w3m[1][j]);
      }
    }
    #pragma unroll
    for (int m=0;m<2;m++){
      short8v r1, r3;
      #pragma unroll
      for (int j=0;j<8;j++){ r1[j]=(short)bfr16(w1m[m][j]); r3[j]=(short)bfr16(w3m[m][j]); }
      wb1[m]=r1; wb3[m]=r3;
    }
    asm volatile("s_waitcnt lgkmcnt(0)" ::: "memory");
    __builtin_amdgcn_sched_barrier(0);
  }
}

// ---------------- grouped RMSNorm * norm_w * sigmoid(gate) -> bf16 y ----------------
__global__ void k_norm_gate(const float* __restrict__ so, const float* __restrict__ gate,
                            const float* __restrict__ nw, __hip_bfloat16* __restrict__ y)
{
  int idx = blockIdx.x*4 + (threadIdx.x>>6);  // (b*N+t)*16+h
  int e = threadIdx.x & 63;
  float o = so[(size_t)idx*64 + e];
  float ss = o*o;
  #pragma unroll
  for (int m=32; m>=1; m>>=1) ss += __shfl_xor(ss, m, 64);
  float rms = rsqrtf(ss*(1.0f/64.0f) + 1e-6f);
  int hh = idx & 15;
  size_t bn = (size_t)(idx >> 4);
  int d = hh*64 + e;
  float g = gate[bn*1024 + d];
  float val = o*rms*nw[d] * (1.0f/(1.0f+__expf(-g)));
  y[bn*1024 + d] = __float2bfloat16(val);
}

extern "C" void kernel_launch(void* const* d_in, const int* in_sizes, int n_in,
                              void* d_out, int out_size, void* d_ws, size_t ws_size,
                              hipStream_t stream)
{
  const float* x   = (const float*)d_in[0];
  const float* Wq  = (const float*)d_in[1];
  const float* Wk  = (const float*)d_in[2];
  const float* Wv  = (const float*)d_in[3];
  const float* Wo  = (const float*)d_in[4];
  const float* w1i = (const float*)d_in[5];
  const float* w3i = (const float*)d_in[6];
  const float* Wlr = (const float*)d_in[7];
  const float* nw  = (const float*)d_in[8];
  const float* Wg1 = (const float*)d_in[9];
  const float* Wg2 = (const float*)d_in[10];
  float* out = (float*)d_out;

  char* p = (char*)d_ws;
  auto take = [&](size_t bytes)->void*{ void* r = (void*)p; p += (bytes + 255) & ~(size_t)255; return r; };
  __hip_bfloat16* xb   = (__hip_bfloat16*)take((size_t)MTOT*D_*2);
  __hip_bfloat16* Wqt  = (__hip_bfloat16*)take((size_t)D_*D_*2);
  __hip_bfloat16* Wkt  = (__hip_bfloat16*)take((size_t)D_*D_*2);
  __hip_bfloat16* Wvt  = (__hip_bfloat16*)take((size_t)D_*D_*2);
  __hip_bfloat16* Wot  = (__hip_bfloat16*)take((size_t)D_*D_*2);
  __hip_bfloat16* Wg2t = (__hip_bfloat16*)take((size_t)D_*HD_*2);
  __hip_bfloat16* WgL  = (__hip_bfloat16*)take((size_t)128*D_*2);
  __hip_bfloat16* t1b  = (__hip_bfloat16*)take((size_t)MTOT*HD_*2);
  float* projt = (float*)take((size_t)MTOT*128*4);
  float* qf  = (float*)take((size_t)MTOT*D_*4);
  float* kf  = (float*)take((size_t)MTOT*D_*4);
  float* vf  = (float*)take((size_t)MTOT*D_*4);
  float* lrb = (float*)take((size_t)MTOT*H_*4);
  float* sob = (float*)take((size_t)MTOT*D_*4);
  __hip_bfloat16* yb = (__hip_bfloat16*)take((size_t)MTOT*D_*2);

  k_cast_bf16<<<MTOT*D_/4/256, 256, 0, stream>>>(x, xb, MTOT*D_/4);
  k_transpose_cast<<<dim3(16,16), 256, 0, stream>>>(Wq, Wqt, D_, D_);
  k_transpose_cast<<<dim3(16,16), 256, 0, stream>>>(Wk, Wkt, D_, D_);
  k_transpose_cast<<<dim3(16,16), 256, 0, stream>>>(Wv, Wvt, D_, D_);
  k_transpose_cast<<<dim3(16,16), 256, 0, stream>>>(Wo, Wot, D_, D_);
  k_transpose_cast<<<dim3(16,1),  256, 0, stream>>>(Wg2, Wg2t, HD_, D_);
  k_prep_wgl<<<512, 256, 0, stream>>>(Wg1, Wlr, WgL);
  // gate bottleneck + lr head in one GEMM: proj = x @ [Wg1 | Wlr | 0]
  k_gemm_bt2<0,0><<<dim3(1,64), 256, 0, stream>>>(xb, WgL, projt, MTOT, 128, D_);
  k_post_gl<<<MTOT/4, 256, 0, stream>>>(projt, t1b, lrb);
  // q,k,v projections (silu on q,k), scattered to [b][h][t][e]
  k_gemm_bt2<1,1><<<dim3(8,64), 256, 0, stream>>>(xb, Wqt, qf, MTOT, D_, D_);
  k_gemm_bt2<1,1><<<dim3(8,64), 256, 0, stream>>>(xb, Wkt, kf, MTOT, D_, D_);
  k_gemm_bt2<0,1><<<dim3(8,64), 256, 0, stream>>>(xb, Wvt, vf, MTOT, D_, D_);
  // gate pre-activation into d_out (free scratch until final GEMM)
  k_gemm_bt2<0,0><<<dim3(8,64), 256, 0, stream>>>(t1b, Wg2t, out, MTOT, D_, HD_);
  k_scan11<<<256, 64, 0, stream>>>(qf, kf, vf, lrb, w1i, w3i, sob);
  k_norm_gate<<<MTOT*H_/4, 256, 0, stream>>>(sob, out, nw, yb);
  k_gemm_bt2<0,0><<<dim3(8,64), 256, 0, stream>>>(yb, Wot, out, MTOT, D_, D_);
}

// Round 13
// 558.801 us; speedup vs baseline: 1.4355x; 1.4355x over previous
//
#include <hip/hip_runtime.h>
#include <hip/hip_bf16.h>

#define B_ 4
#define N_ 2048
#define D_ 1024
#define H_ 16
#define HD_ 64
#define MTOT (B_*N_)   // 8192
#define CH_ 16         // scan chunk size
#define NCH_ (N_/CH_)  // 128

typedef __attribute__((ext_vector_type(8))) short short8v;
typedef __attribute__((ext_vector_type(4))) float f32x4;

// fast sigmoid: raw v_rcp_f32 (~1 ulp), avoids IEEE div sequence on the serial chain
__device__ __forceinline__ float fsig(float x){
  return __builtin_amdgcn_rcpf(1.0f + __expf(-x));
}

// ---------------- cast x -> bf16 (vectorized) ----------------
__global__ void k_cast_bf16(const float* __restrict__ in, __hip_bfloat16* __restrict__ out, int n4){
  int i = blockIdx.x*256 + threadIdx.x;
  if (i >= n4) return;
  float4 vv = ((const float4*)in)[i];
  __hip_bfloat16 b0 = __float2bfloat16(vv.x), b1 = __float2bfloat16(vv.y),
                 b2 = __float2bfloat16(vv.z), b3 = __float2bfloat16(vv.w);
  ushort4 o;
  o.x = *(const unsigned short*)&b0; o.y = *(const unsigned short*)&b1;
  o.z = *(const unsigned short*)&b2; o.w = *(const unsigned short*)&b3;
  ((ushort4*)out)[i] = o;
}

// ---------------- transpose + cast: out[c][r] = in[r][c] ----------------
__global__ void k_transpose_cast(const float* __restrict__ in, __hip_bfloat16* __restrict__ out,
                                 int R, int C){
  __shared__ float tile[64][65];
  int r0 = blockIdx.y*64, c0 = blockIdx.x*64;
  int tid = threadIdx.x;
  #pragma unroll
  for (int i=0;i<16;i++){ int idx = tid + i*256; int rr = idx>>6, cc = idx&63;
    tile[rr][cc] = in[(size_t)(r0+rr)*C + (c0+cc)]; }
  __syncthreads();
  #pragma unroll
  for (int i=0;i<16;i++){ int idx = tid + i*256; int rr = idx>>6, cc = idx&63;
    out[(size_t)(c0+rr)*R + (r0+cc)] = __float2bfloat16(tile[cc][rr]); }
}

// ---------------- pack gate/lr weights: WgL[128][1024] = [Wg1^T ; Wlr^T ; 0] ----------------
__global__ void k_prep_wgl(const float* __restrict__ Wg1, const float* __restrict__ Wlr,
                           __hip_bfloat16* __restrict__ WgL){
  int idx = blockIdx.x*256 + threadIdx.x;   // 0..131071
  int r = idx >> 10, d = idx & 1023;
  float v = 0.f;
  if (r < 64) v = Wg1[(size_t)d*64 + r];
  else if (r < 80) v = Wlr[(size_t)d*16 + (r-64)];
  WgL[idx] = __float2bfloat16(v);
}

// ---------------- post: proj[8192][128] -> t1 bf16 (cols 0-63), lr = 0.01*sigmoid (cols 64-79) ----
__global__ void k_post_gl(const float* __restrict__ proj, __hip_bfloat16* __restrict__ t1,
                          float* __restrict__ lrout){
  int m = blockIdx.x*4 + (threadIdx.x>>6);
  int e = threadIdx.x & 63;
  float val = proj[(size_t)m*128 + e];
  t1[(size_t)m*64 + e] = __float2bfloat16(val);
  if (e < 16){
    float s = proj[(size_t)m*128 + 64 + e];
    lrout[(size_t)m*16 + e] = 0.01f*fsig(s);
  }
}

// ---------------- async global->LDS helper (16B per lane, dest = base + lane*16) ----------------
__device__ __forceinline__ void gl2lds16(const void* g, void* l){
  __builtin_amdgcn_global_load_lds((const __attribute__((address_space(1))) void*)g,
                                   (__attribute__((address_space(3))) void*)l, 16, 0, 0);
}

// ---------------- bf16 MFMA GEMM with global_load_lds staging ----------------
template<int ACT, int LAYOUT>
__global__ __launch_bounds__(256,2) void k_gemm_bt2(
    const __hip_bfloat16* __restrict__ A, const __hip_bfloat16* __restrict__ BT,
    float* __restrict__ C, int M, int N, int K)
{
  __shared__ short As[128*32];
  __shared__ short Bs[128*32];
  const int n0 = blockIdx.x*128, m0 = blockIdx.y*128;
  const int tid = threadIdx.x, lane = tid & 63, wid = tid >> 6;
  const int wm = wid >> 1, wn = wid & 1;
  const short* Aps = (const short*)A;
  const short* Bps = (const short*)BT;
  f32x4 acc[4][4] = {};
  const int srow = wid*32 + (lane>>2);
  const int scol = (lane&3)*8;
  const size_t aoff0 = (size_t)(m0+srow)*K + scol;
  const size_t boff0 = (size_t)(n0+srow)*K + scol;
  short* lA = As + wid*1024;
  short* lB = Bs + wid*1024;
  const int row = lane & 15, kq = (lane >> 4)*8;
  for (int kk = 0; kk < K; kk += 32) {
    __syncthreads();
    gl2lds16(Aps + aoff0 + kk,                 lA);
    gl2lds16(Aps + aoff0 + (size_t)16*K + kk,  lA + 512);
    gl2lds16(Bps + boff0 + kk,                 lB);
    gl2lds16(Bps + boff0 + (size_t)16*K + kk,  lB + 512);
    __syncthreads();
    short8v af[4], bfr[4];
    #pragma unroll
    for (int i=0;i<4;i++) af[i]  = *(const short8v*)(As + (wm*64 + i*16 + row)*32 + kq);
    #pragma unroll
    for (int j=0;j<4;j++) bfr[j] = *(const short8v*)(Bs + (wn*64 + j*16 + row)*32 + kq);
    #pragma unroll
    for (int i=0;i<4;i++)
      #pragma unroll
      for (int j=0;j<4;j++)
        acc[i][j] = __builtin_amdgcn_mfma_f32_16x16x32_bf16(af[i], bfr[j], acc[i][j], 0, 0, 0);
  }
  #pragma unroll
  for (int i=0;i<4;i++){
    #pragma unroll
    for (int j=0;j<4;j++){
      int col = n0 + wn*64 + j*16 + (lane & 15);
      #pragma unroll
      for (int qq=0; qq<4; ++qq){
        int rowg = m0 + wm*64 + i*16 + (lane>>4)*4 + qq;
        float val = acc[i][j][qq];
        if (ACT==1) val = val*fsig(val);
        if (LAYOUT==0) {
          C[(size_t)rowg*N + col] = val;
        } else {
          size_t oidx = ((((size_t)(rowg>>11))*16 + (col>>6))*(size_t)N_ + (size_t)(rowg & 2047))*64
                        + (size_t)(col & 63);
          C[oidx] = val;
        }
      }
    }
  }
}

// ---------------- helpers for chunked scan ----------------
__device__ __forceinline__ unsigned short bfr16(float x){
  __hip_bfloat16 b = __float2bfloat16(x);
  return *(unsigned short*)&b;
}
__device__ __forceinline__ short8v cvt_frag(const float4 a, const float4 c){
  short8v r;
  r[0]=(short)bfr16(a.x); r[1]=(short)bfr16(a.y); r[2]=(short)bfr16(a.z); r[3]=(short)bfr16(a.w);
  r[4]=(short)bfr16(c.x); r[5]=(short)bfr16(c.y); r[6]=(short)bfr16(c.z); r[7]=(short)bfr16(c.w);
  return r;
}

// ---------------- chunked fast-weight scan v8 + rcpf sigmoid ----------------
__global__ __launch_bounds__(256,1) void k_scan8(
    const float* __restrict__ q, const float* __restrict__ k, const float* __restrict__ v,
    const float* __restrict__ lr, const float* __restrict__ w1i, const float* __restrict__ w3i,
    float* __restrict__ so)
{
  const int blk = blockIdx.x;            // 0..255
  const int bh  = blk >> 2;              // b*16+h
  const int sl  = blk & 3;               // e-slab
  const int b = bh >> 4, h = bh & 15;
  const int e0 = sl*16;
  const int tid = threadIdx.x, lane = tid & 63, wid = tid >> 6;
  const int tA = lane & 15, ks8 = (lane >> 4)*8;

  __shared__ __align__(16) __hip_bfloat16 Wb1[16*64];   // mirror [e][d], XOR-swizzled
  __shared__ __align__(16) __hip_bfloat16 Wb3[16*64];
  __shared__ __align__(16) float KW1e[256], KW3e[256];  // [e][t], swizzled 16B slots
  __shared__ __align__(16) float QW1[256], QW3[256];    // [t][e]
  __shared__ __align__(16) float GKK[256], GQK[256];    // [t][s]
  __shared__ __align__(16) float C13[512];              // [s][e][{c1,c3}]

  const int we = tid & 15;
  const int wd = (tid >> 4) * 4;
  float w1r[4], w3r[4];
  {
    const float* w1p = w1i + (size_t)h*HD_*HD_ + e0 + we;
    const float* w3p = w3i + (size_t)h*HD_*HD_ + e0 + we;
    #pragma unroll
    for (int j=0;j<4;j++){ w1r[j] = w1p[(size_t)(wd+j)*64]; w3r[j] = w3p[(size_t)(wd+j)*64]; }
  }
  const int mir_off = we*128 + ((wd*2) ^ ((we&7)<<4));  // byte offset, 8B aligned
  auto write_mirrors = [&](){
    uint2 p1, p3;
    p1.x = (unsigned)bfr16(w1r[0]) | ((unsigned)bfr16(w1r[1])<<16);
    p1.y = (unsigned)bfr16(w1r[2]) | ((unsigned)bfr16(w1r[3])<<16);
    p3.x = (unsigned)bfr16(w3r[0]) | ((unsigned)bfr16(w3r[1])<<16);
    p3.y = (unsigned)bfr16(w3r[2]) | ((unsigned)bfr16(w3r[3])<<16);
    *(uint2*)((char*)Wb1 + mir_off) = p1;
    *(uint2*)((char*)Wb3 + mir_off) = p3;
  };
  write_mirrors();

  const float* kfb = k + (size_t)bh*N_*64;
  const float* qfb = q + (size_t)bh*N_*64;
  const float* vfb = v + (size_t)bh*N_*64;
  const float* lrp = lr + ((size_t)b*N_)*16 + h;
  float* sob = so + (((size_t)b*N_)*16 + h)*64 + e0;

  auto mir_read = [&](const __hip_bfloat16* Wm, int m)->short8v{
    return *(const short8v*)((const char*)Wm + tA*128 + (((m*32+ks8)*2) ^ ((tA&7)<<4)));
  };

  float4 fA0,fA1,fA2,fA3;          // wave1: k frags; wave2: q frags; wave3: k frags
  float4 fB0,fB1,fB2,fB3;          // wave3: q frags
  float  vvr[16], lrr[16];         // wave0 lanes<16

  if (wid >= 1) {
    const float* xr = ((wid==2) ? qfb : kfb) + (size_t)tA*64;
    fA0 = *(const float4*)(xr+ks8);    fA1 = *(const float4*)(xr+ks8+4);
    fA2 = *(const float4*)(xr+32+ks8); fA3 = *(const float4*)(xr+32+ks8+4);
    if (wid==3){
      const float* qr = qfb + (size_t)tA*64;
      fB0 = *(const float4*)(qr+ks8);    fB1 = *(const float4*)(qr+ks8+4);
      fB2 = *(const float4*)(qr+32+ks8); fB3 = *(const float4*)(qr+32+ks8+4);
    }
  } else if (lane < 16) {
    #pragma unroll
    for (int t=0;t<CH_;++t){
      vvr[t] = vfb[(size_t)t*64 + e0 + lane];
      lrr[t] = lrp[(size_t)t*16];
    }
  }
  __syncthreads();

  #pragma unroll 1
  for (int c = 0; c < NCH_; ++c) {
    const int t0 = c*CH_;

    // ---- phase A: MFMA products from prefetched regs (waves 1-3) ----
    if (wid == 1) {
      short8v af0 = cvt_frag(fA0,fA1), af1 = cvt_frag(fA2,fA3);
      const int slot = (((lane>>4)*4) ^ ((( tA>>1)&3)<<2));   // swizzled 16B slot in row tA
      f32x4 acc = {};
      acc = __builtin_amdgcn_mfma_f32_16x16x32_bf16(af0, mir_read(Wb1,0), acc, 0,0,0);
      acc = __builtin_amdgcn_mfma_f32_16x16x32_bf16(af1, mir_read(Wb1,1), acc, 0,0,0);
      *(f32x4*)&KW1e[tA*16 + slot] = acc;
      f32x4 ac3 = {};
      ac3 = __builtin_amdgcn_mfma_f32_16x16x32_bf16(af0, mir_read(Wb3,0), ac3, 0,0,0);
      ac3 = __builtin_amdgcn_mfma_f32_16x16x32_bf16(af1, mir_read(Wb3,1), ac3, 0,0,0);
      *(f32x4*)&KW3e[tA*16 + slot] = ac3;
    } else if (wid == 2) {
      short8v af0 = cvt_frag(fA0,fA1), af1 = cvt_frag(fA2,fA3);
      f32x4 acc = {};
      acc = __builtin_amdgcn_mfma_f32_16x16x32_bf16(af0, mir_read(Wb1,0), acc, 0,0,0);
      acc = __builtin_amdgcn_mfma_f32_16x16x32_bf16(af1, mir_read(Wb1,1), acc, 0,0,0);
      #pragma unroll
      for (int qq=0;qq<4;++qq) QW1[((lane>>4)*4+qq)*16 + tA] = acc[qq];   // t-major
      f32x4 ac3 = {};
      ac3 = __builtin_amdgcn_mfma_f32_16x16x32_bf16(af0, mir_read(Wb3,0), ac3, 0,0,0);
      ac3 = __builtin_amdgcn_mfma_f32_16x16x32_bf16(af1, mir_read(Wb3,1), ac3, 0,0,0);
      #pragma unroll
      for (int qq=0;qq<4;++qq) QW3[((lane>>4)*4+qq)*16 + tA] = ac3[qq];
    } else if (wid == 3) {
      short8v af0 = cvt_frag(fA0,fA1), af1 = cvt_frag(fA2,fA3);
      short8v aq0 = cvt_frag(fB0,fB1), aq1 = cvt_frag(fB2,fB3);
      f32x4 acc = {};
      acc = __builtin_amdgcn_mfma_f32_16x16x32_bf16(af0, af0, acc, 0,0,0);
      acc = __builtin_amdgcn_mfma_f32_16x16x32_bf16(af1, af1, acc, 0,0,0);
      #pragma unroll
      for (int qq=0;qq<4;++qq) GKK[((lane>>4)*4+qq)*16 + tA] = acc[qq];
      f32x4 ac2 = {};
      ac2 = __builtin_amdgcn_mfma_f32_16x16x32_bf16(aq0, af0, ac2, 0,0,0);
      ac2 = __builtin_amdgcn_mfma_f32_16x16x32_bf16(aq1, af1, ac2, 0,0,0);
      #pragma unroll
      for (int qq=0;qq<4;++qq) GQK[((lane>>4)*4+qq)*16 + tA] = ac2[qq];
    }
    __syncthreads();   // bar1: A results visible

    // ---- phase B window ----
    const int tn0 = ((c+1 < NCH_) ? c+1 : c) * CH_;
    if (wid >= 1) {
      // issue chunk c+1 prefetch; park at bar2 while loads fly under wave0's B
      const float* xr = ((wid==2) ? qfb : kfb) + (size_t)(tn0+tA)*64;
      fA0 = *(const float4*)(xr+ks8);    fA1 = *(const float4*)(xr+ks8+4);
      fA2 = *(const float4*)(xr+32+ks8); fA3 = *(const float4*)(xr+32+ks8+4);
      if (wid==3){
        const float* qr = qfb + (size_t)(tn0+tA)*64;
        fB0 = *(const float4*)(qr+ks8);    fB1 = *(const float4*)(qr+ks8+4);
        fB2 = *(const float4*)(qr+32+ks8); fB3 = *(const float4*)(qr+32+ks8+4);
      }
    } else if (lane < 16) {
      // issue c+1 v/lr loads (land during serial B)
      float vvn[16], lrn[16];
      #pragma unroll
      for (int t=0;t<CH_;++t){
        vvn[t] = vfb[(size_t)(tn0+t)*64 + e0 + lane];
        lrn[t] = lrp[(size_t)(tn0+t)*16];
      }
      // preload this lane's KW rows (e = lane) into accumulators (undo slot swizzle)
      float a1[16], a3[16];
      const int swr = ((lane>>1)&3)<<2;
      #pragma unroll
      for (int i2=0;i2<4;i2++){
        f32x4 x1 = *(const f32x4*)&KW1e[lane*16 + ((i2*4) ^ swr)];
        f32x4 x3 = *(const f32x4*)&KW3e[lane*16 + ((i2*4) ^ swr)];
        a1[i2*4+0]=x1[0]; a1[i2*4+1]=x1[1]; a1[i2*4+2]=x1[2]; a1[i2*4+3]=x1[3];
        a3[i2*4+0]=x3[0]; a3[i2*4+1]=x3[1]; a3[i2*4+2]=x3[2]; a3[i2*4+3]=x3[3];
      }
      // GKK row pipeline (row t needed at token t; symmetric so row == column)
      f32x4 grow[3][4];
      #pragma unroll
      for (int i2=0;i2<4;i2++){
        grow[0][i2] = *(const f32x4*)&GKK[ 0 + i2*4];
        grow[1][i2] = *(const f32x4*)&GKK[16 + i2*4];
        grow[2][i2] = *(const f32x4*)&GKK[32 + i2*4];
      }
      #pragma unroll
      for (int t = 0; t < CH_; ++t) {
        const float h1 = a1[t], h3 = a3[t];   // fully corrected by eager updates
        const float sg = fsig(h1);
        const float s1 = h1*sg;
        const float er = fmaf(s1, h3, -vvr[t]);
        const float ds = sg*fmaf(h1, 1.0f - sg, 1.0f);
        const float lt = lrr[t];
        float2 cc; cc.x = lt*(er*h3*ds); cc.y = lt*(er*s1);
        *(float2*)&C13[(t*16+lane)*2] = cc;
        // eager: push correction of token t into all future accumulators
        #pragma unroll
        for (int t2 = t+1; t2 < CH_; ++t2) {
          const float g = grow[t%3][t2>>2][t2&3];
          a1[t2] = fmaf(-g, cc.x, a1[t2]);
          a3[t2] = fmaf(-g, cc.y, a3[t2]);
        }
        if (t + 3 < CH_) {   // refill consumed slot with row t+3 (used 3 tokens later)
          #pragma unroll
          for (int i2=0;i2<4;i2++) grow[(t+3)%3][i2] = *(const f32x4*)&GKK[(t+3)*16 + i2*4];
        }
      }
      #pragma unroll
      for (int t=0;t<CH_;++t){ vvr[t]=vvn[t]; lrr[t]=lrn[t]; }
    }
    __syncthreads();   // bar2: C13 visible

    // ---- phase O: all 256 threads, one (t,e) each; masked full unroll ----
    {
      const int ot = tid >> 4, oe = tid & 15;
      float o1 = QW1[ot*16+oe], o3 = QW3[ot*16+oe];
      #pragma unroll
      for (int s = 0; s < CH_; ++s) {
        const float gl2 = GQK[ot*16+s];
        const float2 cc = *(const float2*)&C13[(s*16+oe)*2];
        const float g = (s <= ot) ? gl2 : 0.0f;
        o1 = fmaf(-g, cc.x, o1);
        o3 = fmaf(-g, cc.y, o3);
      }
      sob[(size_t)(t0+ot)*(H_*HD_) + oe] = (o1*fsig(o1))*o3;
    }

    // ---- phase C: rank-16 W update + rewrite mirror ----
    #pragma unroll
    for (int s = 0; s < CH_; ++s) {
      const float2 cc = *(const float2*)&C13[(s*16+we)*2];
      const float4 ks = *(const float4*)(kfb + (size_t)(t0+s)*64 + wd);
      w1r[0] = fmaf(-ks.x, cc.x, w1r[0]); w1r[1] = fmaf(-ks.y, cc.x, w1r[1]);
      w1r[2] = fmaf(-ks.z, cc.x, w1r[2]); w1r[3] = fmaf(-ks.w, cc.x, w1r[3]);
      w3r[0] = fmaf(-ks.x, cc.y, w3r[0]); w3r[1] = fmaf(-ks.y, cc.y, w3r[1]);
      w3r[2] = fmaf(-ks.z, cc.y, w3r[2]); w3r[3] = fmaf(-ks.w, cc.y, w3r[3]);
    }
    write_mirrors();
    __syncthreads();   // bar3: mirror ready for A(c+1)
  }
}

// ---------------- grouped RMSNorm * norm_w * sigmoid(gate) -> bf16 y ----------------
__global__ void k_norm_gate(const float* __restrict__ so, const float* __restrict__ gate,
                            const float* __restrict__ nw, __hip_bfloat16* __restrict__ y)
{
  int idx = blockIdx.x*4 + (threadIdx.x>>6);  // (b*N+t)*16+h
  int e = threadIdx.x & 63;
  float o = so[(size_t)idx*64 + e];
  float ss = o*o;
  #pragma unroll
  for (int m=32; m>=1; m>>=1) ss += __shfl_xor(ss, m, 64);
  float rms = rsqrtf(ss*(1.0f/64.0f) + 1e-6f);
  int hh = idx & 15;
  size_t bn = (size_t)(idx >> 4);
  int d = hh*64 + e;
  float g = gate[bn*1024 + d];
  float val = o*rms*nw[d] * fsig(g);
  y[bn*1024 + d] = __float2bfloat16(val);
}

extern "C" void kernel_launch(void* const* d_in, const int* in_sizes, int n_in,
                              void* d_out, int out_size, void* d_ws, size_t ws_size,
                              hipStream_t stream)
{
  const float* x   = (const float*)d_in[0];
  const float* Wq  = (const float*)d_in[1];
  const float* Wk  = (const float*)d_in[2];
  const float* Wv  = (const float*)d_in[3];
  const float* Wo  = (const float*)d_in[4];
  const float* w1i = (const float*)d_in[5];
  const float* w3i = (const float*)d_in[6];
  const float* Wlr = (const float*)d_in[7];
  const float* nw  = (const float*)d_in[8];
  const float* Wg1 = (const float*)d_in[9];
  const float* Wg2 = (const float*)d_in[10];
  float* out = (float*)d_out;

  char* p = (char*)d_ws;
  auto take = [&](size_t bytes)->void*{ void* r = (void*)p; p += (bytes + 255) & ~(size_t)255; return r; };
  __hip_bfloat16* xb   = (__hip_bfloat16*)take((size_t)MTOT*D_*2);
  __hip_bfloat16* Wqt  = (__hip_bfloat16*)take((size_t)D_*D_*2);
  __hip_bfloat16* Wkt  = (__hip_bfloat16*)take((size_t)D_*D_*2);
  __hip_bfloat16* Wvt  = (__hip_bfloat16*)take((size_t)D_*D_*2);
  __hip_bfloat16* Wot  = (__hip_bfloat16*)take((size_t)D_*D_*2);
  __hip_bfloat16* Wg2t = (__hip_bfloat16*)take((size_t)D_*HD_*2);
  __hip_bfloat16* WgL  = (__hip_bfloat16*)take((size_t)128*D_*2);
  __hip_bfloat16* t1b  = (__hip_bfloat16*)take((size_t)MTOT*HD_*2);
  float* projt = (float*)take((size_t)MTOT*128*4);
  float* qf  = (float*)take((size_t)MTOT*D_*4);
  float* kf  = (float*)take((size_t)MTOT*D_*4);
  float* vf  = (float*)take((size_t)MTOT*D_*4);
  float* lrb = (float*)take((size_t)MTOT*H_*4);
  float* sob = (float*)take((size_t)MTOT*D_*4);
  __hip_bfloat16* yb = (__hip_bfloat16*)take((size_t)MTOT*D_*2);

  k_cast_bf16<<<MTOT*D_/4/256, 256, 0, stream>>>(x, xb, MTOT*D_/4);
  k_transpose_cast<<<dim3(16,16), 256, 0, stream>>>(Wq, Wqt, D_, D_);
  k_transpose_cast<<<dim3(16,16), 256, 0, stream>>>(Wk, Wkt, D_, D_);
  k_transpose_cast<<<dim3(16,16), 256, 0, stream>>>(Wv, Wvt, D_, D_);
  k_transpose_cast<<<dim3(16,16), 256, 0, stream>>>(Wo, Wot, D_, D_);
  k_transpose_cast<<<dim3(16,1),  256, 0, stream>>>(Wg2, Wg2t, HD_, D_);
  k_prep_wgl<<<512, 256, 0, stream>>>(Wg1, Wlr, WgL);
  // gate bottleneck + lr head in one GEMM: proj = x @ [Wg1 | Wlr | 0]
  k_gemm_bt2<0,0><<<dim3(1,64), 256, 0, stream>>>(xb, WgL, projt, MTOT, 128, D_);
  k_post_gl<<<MTOT/4, 256, 0, stream>>>(projt, t1b, lrb);
  // q,k,v projections (silu on q,k), scattered to [b][h][t][e]
  k_gemm_bt2<1,1><<<dim3(8,64), 256, 0, stream>>>(xb, Wqt, qf, MTOT, D_, D_);
  k_gemm_bt2<1,1><<<dim3(8,64), 256, 0, stream>>>(xb, Wkt, kf, MTOT, D_, D_);
  k_gemm_bt2<0,1><<<dim3(8,64), 256, 0, stream>>>(xb, Wvt, vf, MTOT, D_, D_);
  // gate pre-activation into d_out (free scratch until final GEMM)
  k_gemm_bt2<0,0><<<dim3(8,64), 256, 0, stream>>>(t1b, Wg2t, out, MTOT, D_, HD_);
  k_scan8<<<256, 256, 0, stream>>>(qf, kf, vf, lrb, w1i, w3i, sob);
  k_norm_gate<<<MTOT*H_/4, 256, 0, stream>>>(sob, out, nw, yb);
  k_gemm_bt2<0,0><<<dim3(8,64), 256, 0, stream>>>(yb, Wot, out, MTOT, D_, D_);
}

// Round 14
// 524.584 us; speedup vs baseline: 1.5291x; 1.0652x over previous
//
#include <hip/hip_runtime.h>
#include <hip/hip_bf16.h>

#define B_ 4
#define N_ 2048
#define D_ 1024
#define H_ 16
#define HD_ 64
#define MTOT (B_*N_)   // 8192
#define CH_ 16         // scan chunk size
#define NCH_ (N_/CH_)  // 128

typedef __attribute__((ext_vector_type(8))) short short8v;
typedef __attribute__((ext_vector_type(4))) float f32x4;

// fast sigmoid: raw v_rcp_f32 (~1 ulp), avoids IEEE div sequence on the serial chain
__device__ __forceinline__ float fsig(float x){
  return __builtin_amdgcn_rcpf(1.0f + __expf(-x));
}

// ---------------- cast x -> bf16 (vectorized) ----------------
__global__ void k_cast_bf16(const float* __restrict__ in, __hip_bfloat16* __restrict__ out, int n4){
  int i = blockIdx.x*256 + threadIdx.x;
  if (i >= n4) return;
  float4 vv = ((const float4*)in)[i];
  __hip_bfloat16 b0 = __float2bfloat16(vv.x), b1 = __float2bfloat16(vv.y),
                 b2 = __float2bfloat16(vv.z), b3 = __float2bfloat16(vv.w);
  ushort4 o;
  o.x = *(const unsigned short*)&b0; o.y = *(const unsigned short*)&b1;
  o.z = *(const unsigned short*)&b2; o.w = *(const unsigned short*)&b3;
  ((ushort4*)out)[i] = o;
}

// ---------------- transpose + cast: out[c][r] = in[r][c] ----------------
__global__ void k_transpose_cast(const float* __restrict__ in, __hip_bfloat16* __restrict__ out,
                                 int R, int C){
  __shared__ float tile[64][65];
  int r0 = blockIdx.y*64, c0 = blockIdx.x*64;
  int tid = threadIdx.x;
  #pragma unroll
  for (int i=0;i<16;i++){ int idx = tid + i*256; int rr = idx>>6, cc = idx&63;
    tile[rr][cc] = in[(size_t)(r0+rr)*C + (c0+cc)]; }
  __syncthreads();
  #pragma unroll
  for (int i=0;i<16;i++){ int idx = tid + i*256; int rr = idx>>6, cc = idx&63;
    out[(size_t)(c0+rr)*R + (r0+cc)] = __float2bfloat16(tile[cc][rr]); }
}

// ---------------- pack gate/lr weights: WgL[128][1024] = [Wg1^T ; Wlr^T ; 0] ----------------
__global__ void k_prep_wgl(const float* __restrict__ Wg1, const float* __restrict__ Wlr,
                           __hip_bfloat16* __restrict__ WgL){
  int idx = blockIdx.x*256 + threadIdx.x;   // 0..131071
  int r = idx >> 10, d = idx & 1023;
  float v = 0.f;
  if (r < 64) v = Wg1[(size_t)d*64 + r];
  else if (r < 80) v = Wlr[(size_t)d*16 + (r-64)];
  WgL[idx] = __float2bfloat16(v);
}

// ---------------- post: proj[8192][128] -> t1 bf16 (cols 0-63), lr = 0.01*sigmoid (cols 64-79) ----
__global__ void k_post_gl(const float* __restrict__ proj, __hip_bfloat16* __restrict__ t1,
                          float* __restrict__ lrout){
  int m = blockIdx.x*4 + (threadIdx.x>>6);
  int e = threadIdx.x & 63;
  float val = proj[(size_t)m*128 + e];
  t1[(size_t)m*64 + e] = __float2bfloat16(val);
  if (e < 16){
    float s = proj[(size_t)m*128 + 64 + e];
    lrout[(size_t)m*16 + e] = 0.01f*fsig(s);
  }
}

// ---------------- async global->LDS helper (16B per lane, dest = base + lane*16) ----------------
__device__ __forceinline__ void gl2lds16(const void* g, void* l){
  __builtin_amdgcn_global_load_lds((const __attribute__((address_space(1))) void*)g,
                                   (__attribute__((address_space(3))) void*)l, 16, 0, 0);
}

// ---------------- bf16 MFMA GEMM with global_load_lds staging ----------------
// LAYOUT 0: C[m*N+col]. LAYOUT 1: scatter [b][h][t][e] (single tensor, ACT=1 silu).
// LAYOUT 2: fused QKV (N=3072): tensor t3=col>>10 -> base + t3*MTOT*D, silu for t3<2.
template<int ACT, int LAYOUT>
__global__ __launch_bounds__(256,2) void k_gemm_bt2(
    const __hip_bfloat16* __restrict__ A, const __hip_bfloat16* __restrict__ BT,
    float* __restrict__ C, int M, int N, int K)
{
  __shared__ short As[128*32];
  __shared__ short Bs[128*32];
  const int n0 = blockIdx.x*128, m0 = blockIdx.y*128;
  const int tid = threadIdx.x, lane = tid & 63, wid = tid >> 6;
  const int wm = wid >> 1, wn = wid & 1;
  const short* Aps = (const short*)A;
  const short* Bps = (const short*)BT;
  f32x4 acc[4][4] = {};
  const int srow = wid*32 + (lane>>2);
  const int scol = (lane&3)*8;
  const size_t aoff0 = (size_t)(m0+srow)*K + scol;
  const size_t boff0 = (size_t)(n0+srow)*K + scol;
  short* lA = As + wid*1024;
  short* lB = Bs + wid*1024;
  const int row = lane & 15, kq = (lane >> 4)*8;
  for (int kk = 0; kk < K; kk += 32) {
    __syncthreads();
    gl2lds16(Aps + aoff0 + kk,                 lA);
    gl2lds16(Aps + aoff0 + (size_t)16*K + kk,  lA + 512);
    gl2lds16(Bps + boff0 + kk,                 lB);
    gl2lds16(Bps + boff0 + (size_t)16*K + kk,  lB + 512);
    __syncthreads();
    short8v af[4], bfr[4];
    #pragma unroll
    for (int i=0;i<4;i++) af[i]  = *(const short8v*)(As + (wm*64 + i*16 + row)*32 + kq);
    #pragma unroll
    for (int j=0;j<4;j++) bfr[j] = *(const short8v*)(Bs + (wn*64 + j*16 + row)*32 + kq);
    #pragma unroll
    for (int i=0;i<4;i++)
      #pragma unroll
      for (int j=0;j<4;j++)
        acc[i][j] = __builtin_amdgcn_mfma_f32_16x16x32_bf16(af[i], bfr[j], acc[i][j], 0, 0, 0);
  }
  #pragma unroll
  for (int i=0;i<4;i++){
    #pragma unroll
    for (int j=0;j<4;j++){
      int col = n0 + wn*64 + j*16 + (lane & 15);
      #pragma unroll
      for (int qq=0; qq<4; ++qq){
        int rowg = m0 + wm*64 + i*16 + (lane>>4)*4 + qq;
        float val = acc[i][j][qq];
        if (LAYOUT==0) {
          if (ACT==1) val = val*fsig(val);
          C[(size_t)rowg*N + col] = val;
        } else if (LAYOUT==1) {
          if (ACT==1) val = val*fsig(val);
          size_t oidx = ((((size_t)(rowg>>11))*16 + (col>>6))*(size_t)N_ + (size_t)(rowg & 2047))*64
                        + (size_t)(col & 63);
          C[oidx] = val;
        } else {
          const int t3 = col >> 10, cc2 = col & 1023;
          if (t3 < 2) val = val*fsig(val);   // silu on q,k; none on v
          size_t oidx = (size_t)t3*((size_t)MTOT*D_)
                      + ((((size_t)(rowg>>11))*16 + (cc2>>6))*(size_t)N_ + (size_t)(rowg & 2047))*64
                      + (size_t)(cc2 & 63);
          C[oidx] = val;
        }
      }
    }
  }
}

// ---------------- helpers for chunked scan ----------------
__device__ __forceinline__ unsigned short bfr16(float x){
  __hip_bfloat16 b = __float2bfloat16(x);
  return *(unsigned short*)&b;
}
__device__ __forceinline__ short8v cvt_frag(const float4 a, const float4 c){
  short8v r;
  r[0]=(short)bfr16(a.x); r[1]=(short)bfr16(a.y); r[2]=(short)bfr16(a.z); r[3]=(short)bfr16(a.w);
  r[4]=(short)bfr16(c.x); r[5]=(short)bfr16(c.y); r[6]=(short)bfr16(c.z); r[7]=(short)bfr16(c.w);
  return r;
}

// ---------------- chunked fast-weight scan v8 + rcpf + LDS k-staging for phase C ----------------
__global__ __launch_bounds__(256,1) void k_scan8(
    const float* __restrict__ q, const float* __restrict__ k, const float* __restrict__ v,
    const float* __restrict__ lr, const float* __restrict__ w1i, const float* __restrict__ w3i,
    float* __restrict__ so)
{
  const int blk = blockIdx.x;            // 0..255
  const int bh  = blk >> 2;              // b*16+h
  const int sl  = blk & 3;               // e-slab
  const int b = bh >> 4, h = bh & 15;
  const int e0 = sl*16;
  const int tid = threadIdx.x, lane = tid & 63, wid = tid >> 6;
  const int tA = lane & 15, ks8 = (lane >> 4)*8;

  __shared__ __align__(16) __hip_bfloat16 Wb1[16*64];   // mirror [e][d], XOR-swizzled
  __shared__ __align__(16) __hip_bfloat16 Wb3[16*64];
  __shared__ __align__(16) float KW1e[256], KW3e[256];  // [e][t], swizzled 16B slots
  __shared__ __align__(16) float QW1[256], QW3[256];    // [t][e]
  __shared__ __align__(16) float GKK[256], GQK[256];    // [t][s]
  __shared__ __align__(16) float C13[512];              // [s][e][{c1,c3}]
  __shared__ __align__(16) float kS[16][68];            // chunk-c k rows (fp32), +4 pad

  const int we = tid & 15;
  const int wd = (tid >> 4) * 4;
  float w1r[4], w3r[4];
  {
    const float* w1p = w1i + (size_t)h*HD_*HD_ + e0 + we;
    const float* w3p = w3i + (size_t)h*HD_*HD_ + e0 + we;
    #pragma unroll
    for (int j=0;j<4;j++){ w1r[j] = w1p[(size_t)(wd+j)*64]; w3r[j] = w3p[(size_t)(wd+j)*64]; }
  }
  const int mir_off = we*128 + ((wd*2) ^ ((we&7)<<4));  // byte offset, 8B aligned
  auto write_mirrors = [&](){
    uint2 p1, p3;
    p1.x = (unsigned)bfr16(w1r[0]) | ((unsigned)bfr16(w1r[1])<<16);
    p1.y = (unsigned)bfr16(w1r[2]) | ((unsigned)bfr16(w1r[3])<<16);
    p3.x = (unsigned)bfr16(w3r[0]) | ((unsigned)bfr16(w3r[1])<<16);
    p3.y = (unsigned)bfr16(w3r[2]) | ((unsigned)bfr16(w3r[3])<<16);
    *(uint2*)((char*)Wb1 + mir_off) = p1;
    *(uint2*)((char*)Wb3 + mir_off) = p3;
  };
  write_mirrors();

  const float* kfb = k + (size_t)bh*N_*64;
  const float* qfb = q + (size_t)bh*N_*64;
  const float* vfb = v + (size_t)bh*N_*64;
  const float* lrp = lr + ((size_t)b*N_)*16 + h;
  float* sob = so + (((size_t)b*N_)*16 + h)*64 + e0;

  auto mir_read = [&](const __hip_bfloat16* Wm, int m)->short8v{
    return *(const short8v*)((const char*)Wm + tA*128 + (((m*32+ks8)*2) ^ ((tA&7)<<4)));
  };

  float4 fA0,fA1,fA2,fA3;          // wave1: k frags; wave2: q frags; wave3: k frags
  float4 fB0,fB1,fB2,fB3;          // wave3: q frags
  float  vvr[16], lrr[16];         // wave0 lanes<16

  if (wid >= 1) {
    const float* xr = ((wid==2) ? qfb : kfb) + (size_t)tA*64;
    fA0 = *(const float4*)(xr+ks8);    fA1 = *(const float4*)(xr+ks8+4);
    fA2 = *(const float4*)(xr+32+ks8); fA3 = *(const float4*)(xr+32+ks8+4);
    if (wid==3){
      const float* qr = qfb + (size_t)tA*64;
      fB0 = *(const float4*)(qr+ks8);    fB1 = *(const float4*)(qr+ks8+4);
      fB2 = *(const float4*)(qr+32+ks8); fB3 = *(const float4*)(qr+32+ks8+4);
    }
  } else if (lane < 16) {
    #pragma unroll
    for (int t=0;t<CH_;++t){
      vvr[t] = vfb[(size_t)t*64 + e0 + lane];
      lrr[t] = lrp[(size_t)t*16];
    }
  }
  __syncthreads();

  #pragma unroll 1
  for (int c = 0; c < NCH_; ++c) {
    const int t0 = c*CH_;

    // ---- phase A: MFMA products from prefetched regs (waves 1-3) ----
    if (wid == 1) {
      // stage chunk-c k rows (fp32) for phase C
      *(float4*)&kS[tA][ks8]      = fA0;
      *(float4*)&kS[tA][ks8+4]    = fA1;
      *(float4*)&kS[tA][32+ks8]   = fA2;
      *(float4*)&kS[tA][32+ks8+4] = fA3;
      short8v af0 = cvt_frag(fA0,fA1), af1 = cvt_frag(fA2,fA3);
      const int slot = (((lane>>4)*4) ^ ((( tA>>1)&3)<<2));   // swizzled 16B slot in row tA
      f32x4 acc = {};
      acc = __builtin_amdgcn_mfma_f32_16x16x32_bf16(af0, mir_read(Wb1,0), acc, 0,0,0);
      acc = __builtin_amdgcn_mfma_f32_16x16x32_bf16(af1, mir_read(Wb1,1), acc, 0,0,0);
      *(f32x4*)&KW1e[tA*16 + slot] = acc;
      f32x4 ac3 = {};
      ac3 = __builtin_amdgcn_mfma_f32_16x16x32_bf16(af0, mir_read(Wb3,0), ac3, 0,0,0);
      ac3 = __builtin_amdgcn_mfma_f32_16x16x32_bf16(af1, mir_read(Wb3,1), ac3, 0,0,0);
      *(f32x4*)&KW3e[tA*16 + slot] = ac3;
    } else if (wid == 2) {
      short8v af0 = cvt_frag(fA0,fA1), af1 = cvt_frag(fA2,fA3);
      f32x4 acc = {};
      acc = __builtin_amdgcn_mfma_f32_16x16x32_bf16(af0, mir_read(Wb1,0), acc, 0,0,0);
      acc = __builtin_amdgcn_mfma_f32_16x16x32_bf16(af1, mir_read(Wb1,1), acc, 0,0,0);
      #pragma unroll
      for (int qq=0;qq<4;++qq) QW1[((lane>>4)*4+qq)*16 + tA] = acc[qq];   // t-major
      f32x4 ac3 = {};
      ac3 = __builtin_amdgcn_mfma_f32_16x16x32_bf16(af0, mir_read(Wb3,0), ac3, 0,0,0);
      ac3 = __builtin_amdgcn_mfma_f32_16x16x32_bf16(af1, mir_read(Wb3,1), ac3, 0,0,0);
      #pragma unroll
      for (int qq=0;qq<4;++qq) QW3[((lane>>4)*4+qq)*16 + tA] = ac3[qq];
    } else if (wid == 3) {
      short8v af0 = cvt_frag(fA0,fA1), af1 = cvt_frag(fA2,fA3);
      short8v aq0 = cvt_frag(fB0,fB1), aq1 = cvt_frag(fB2,fB3);
      f32x4 acc = {};
      acc = __builtin_amdgcn_mfma_f32_16x16x32_bf16(af0, af0, acc, 0,0,0);
      acc = __builtin_amdgcn_mfma_f32_16x16x32_bf16(af1, af1, acc, 0,0,0);
      #pragma unroll
      for (int qq=0;qq<4;++qq) GKK[((lane>>4)*4+qq)*16 + tA] = acc[qq];
      f32x4 ac2 = {};
      ac2 = __builtin_amdgcn_mfma_f32_16x16x32_bf16(aq0, af0, ac2, 0,0,0);
      ac2 = __builtin_amdgcn_mfma_f32_16x16x32_bf16(aq1, af1, ac2, 0,0,0);
      #pragma unroll
      for (int qq=0;qq<4;++qq) GQK[((lane>>4)*4+qq)*16 + tA] = ac2[qq];
    }
    __syncthreads();   // bar1: A results visible

    // ---- phase B window ----
    const int tn0 = ((c+1 < NCH_) ? c+1 : c) * CH_;
    if (wid >= 1) {
      // issue chunk c+1 prefetch; park at bar2 while loads fly under wave0's B
      const float* xr = ((wid==2) ? qfb : kfb) + (size_t)(tn0+tA)*64;
      fA0 = *(const float4*)(xr+ks8);    fA1 = *(const float4*)(xr+ks8+4);
      fA2 = *(const float4*)(xr+32+ks8); fA3 = *(const float4*)(xr+32+ks8+4);
      if (wid==3){
        const float* qr = qfb + (size_t)(tn0+tA)*64;
        fB0 = *(const float4*)(qr+ks8);    fB1 = *(const float4*)(qr+ks8+4);
        fB2 = *(const float4*)(qr+32+ks8); fB3 = *(const float4*)(qr+32+ks8+4);
      }
    } else if (lane < 16) {
      // issue c+1 v/lr loads (land during serial B)
      float vvn[16], lrn[16];
      #pragma unroll
      for (int t=0;t<CH_;++t){
        vvn[t] = vfb[(size_t)(tn0+t)*64 + e0 + lane];
        lrn[t] = lrp[(size_t)(tn0+t)*16];
      }
      // preload this lane's KW rows (e = lane) into accumulators (undo slot swizzle)
      float a1[16], a3[16];
      const int swr = ((lane>>1)&3)<<2;
      #pragma unroll
      for (int i2=0;i2<4;i2++){
        f32x4 x1 = *(const f32x4*)&KW1e[lane*16 + ((i2*4) ^ swr)];
        f32x4 x3 = *(const f32x4*)&KW3e[lane*16 + ((i2*4) ^ swr)];
        a1[i2*4+0]=x1[0]; a1[i2*4+1]=x1[1]; a1[i2*4+2]=x1[2]; a1[i2*4+3]=x1[3];
        a3[i2*4+0]=x3[0]; a3[i2*4+1]=x3[1]; a3[i2*4+2]=x3[2]; a3[i2*4+3]=x3[3];
      }
      // GKK row pipeline (row t needed at token t; symmetric so row == column)
      f32x4 grow[3][4];
      #pragma unroll
      for (int i2=0;i2<4;i2++){
        grow[0][i2] = *(const f32x4*)&GKK[ 0 + i2*4];
        grow[1][i2] = *(const f32x4*)&GKK[16 + i2*4];
        grow[2][i2] = *(const f32x4*)&GKK[32 + i2*4];
      }
      #pragma unroll
      for (int t = 0; t < CH_; ++t) {
        const float h1 = a1[t], h3 = a3[t];   // fully corrected by eager updates
        const float sg = fsig(h1);
        const float s1 = h1*sg;
        const float er = fmaf(s1, h3, -vvr[t]);
        const float ds = sg*fmaf(h1, 1.0f - sg, 1.0f);
        const float lt = lrr[t];
        float2 cc; cc.x = lt*(er*h3*ds); cc.y = lt*(er*s1);
        *(float2*)&C13[(t*16+lane)*2] = cc;
        // eager: push correction of token t into all future accumulators
        #pragma unroll
        for (int t2 = t+1; t2 < CH_; ++t2) {
          const float g = grow[t%3][t2>>2][t2&3];
          a1[t2] = fmaf(-g, cc.x, a1[t2]);
          a3[t2] = fmaf(-g, cc.y, a3[t2]);
        }
        if (t + 3 < CH_) {   // refill consumed slot with row t+3 (used 3 tokens later)
          #pragma unroll
          for (int i2=0;i2<4;i2++) grow[(t+3)%3][i2] = *(const f32x4*)&GKK[(t+3)*16 + i2*4];
        }
      }
      #pragma unroll
      for (int t=0;t<CH_;++t){ vvr[t]=vvn[t]; lrr[t]=lrn[t]; }
    }
    __syncthreads();   // bar2: C13 visible

    // ---- phase O: all 256 threads, one (t,e) each; masked full unroll ----
    {
      const int ot = tid >> 4, oe = tid & 15;
      float o1 = QW1[ot*16+oe], o3 = QW3[ot*16+oe];
      #pragma unroll
      for (int s = 0; s < CH_; ++s) {
        const float gl2 = GQK[ot*16+s];
        const float2 cc = *(const float2*)&C13[(s*16+oe)*2];
        const float g = (s <= ot) ? gl2 : 0.0f;
        o1 = fmaf(-g, cc.x, o1);
        o3 = fmaf(-g, cc.y, o3);
      }
      sob[(size_t)(t0+ot)*(H_*HD_) + oe] = (o1*fsig(o1))*o3;
    }

    // ---- phase C: rank-16 W update (k rows from LDS) + rewrite mirror ----
    #pragma unroll
    for (int s = 0; s < CH_; ++s) {
      const float2 cc = *(const float2*)&C13[(s*16+we)*2];
      const float4 ks = *(const float4*)&kS[s][wd];
      w1r[0] = fmaf(-ks.x, cc.x, w1r[0]); w1r[1] = fmaf(-ks.y, cc.x, w1r[1]);
      w1r[2] = fmaf(-ks.z, cc.x, w1r[2]); w1r[3] = fmaf(-ks.w, cc.x, w1r[3]);
      w3r[0] = fmaf(-ks.x, cc.y, w3r[0]); w3r[1] = fmaf(-ks.y, cc.y, w3r[1]);
      w3r[2] = fmaf(-ks.z, cc.y, w3r[2]); w3r[3] = fmaf(-ks.w, cc.y, w3r[3]);
    }
    write_mirrors();
    __syncthreads();   // bar3: mirror ready for A(c+1)
  }
}

// ---------------- grouped RMSNorm * norm_w * sigmoid(gate) -> bf16 y ----------------
__global__ void k_norm_gate(const float* __restrict__ so, const float* __restrict__ gate,
                            const float* __restrict__ nw, __hip_bfloat16* __restrict__ y)
{
  int idx = blockIdx.x*4 + (threadIdx.x>>6);  // (b*N+t)*16+h
  int e = threadIdx.x & 63;
  float o = so[(size_t)idx*64 + e];
  float ss = o*o;
  #pragma unroll
  for (int m=32; m>=1; m>>=1) ss += __shfl_xor(ss, m, 64);
  float rms = rsqrtf(ss*(1.0f/64.0f) + 1e-6f);
  int hh = idx & 15;
  size_t bn = (size_t)(idx >> 4);
  int d = hh*64 + e;
  float g = gate[bn*1024 + d];
  float val = o*rms*nw[d] * fsig(g);
  y[bn*1024 + d] = __float2bfloat16(val);
}

extern "C" void kernel_launch(void* const* d_in, const int* in_sizes, int n_in,
                              void* d_out, int out_size, void* d_ws, size_t ws_size,
                              hipStream_t stream)
{
  const float* x   = (const float*)d_in[0];
  const float* Wq  = (const float*)d_in[1];
  const float* Wk  = (const float*)d_in[2];
  const float* Wv  = (const float*)d_in[3];
  const float* Wo  = (const float*)d_in[4];
  const float* w1i = (const float*)d_in[5];
  const float* w3i = (const float*)d_in[6];
  const float* Wlr = (const float*)d_in[7];
  const float* nw  = (const float*)d_in[8];
  const float* Wg1 = (const float*)d_in[9];
  const float* Wg2 = (const float*)d_in[10];
  float* out = (float*)d_out;

  char* p = (char*)d_ws;
  auto take = [&](size_t bytes)->void*{ void* r = (void*)p; p += (bytes + 255) & ~(size_t)255; return r; };
  __hip_bfloat16* xb    = (__hip_bfloat16*)take((size_t)MTOT*D_*2);
  __hip_bfloat16* WqkvT = (__hip_bfloat16*)take((size_t)3*D_*D_*2);   // [Wq^T ; Wk^T ; Wv^T]
  __hip_bfloat16* Wot   = (__hip_bfloat16*)take((size_t)D_*D_*2);
  __hip_bfloat16* Wg2t  = (__hip_bfloat16*)take((size_t)D_*HD_*2);
  __hip_bfloat16* WgL   = (__hip_bfloat16*)take((size_t)128*D_*2);
  __hip_bfloat16* t1b   = (__hip_bfloat16*)take((size_t)MTOT*HD_*2);
  float* projt = (float*)take((size_t)MTOT*128*4);
  float* qf  = (float*)take((size_t)MTOT*D_*4);   // qf,kf,vf contiguous (32MB each, 256-aligned)
  float* kf  = (float*)take((size_t)MTOT*D_*4);
  float* vf  = (float*)take((size_t)MTOT*D_*4);
  float* lrb = (float*)take((size_t)MTOT*H_*4);
  float* sob = (float*)take((size_t)MTOT*D_*4);
  __hip_bfloat16* yb = (__hip_bfloat16*)take((size_t)MTOT*D_*2);
  (void)kf; (void)vf;

  k_cast_bf16<<<MTOT*D_/4/256, 256, 0, stream>>>(x, xb, MTOT*D_/4);
  k_transpose_cast<<<dim3(16,16), 256, 0, stream>>>(Wq, WqkvT,             D_, D_);
  k_transpose_cast<<<dim3(16,16), 256, 0, stream>>>(Wk, WqkvT + D_*D_,     D_, D_);
  k_transpose_cast<<<dim3(16,16), 256, 0, stream>>>(Wv, WqkvT + 2*D_*D_,   D_, D_);
  k_transpose_cast<<<dim3(16,16), 256, 0, stream>>>(Wo, Wot, D_, D_);
  k_transpose_cast<<<dim3(16,1),  256, 0, stream>>>(Wg2, Wg2t, HD_, D_);
  k_prep_wgl<<<512, 256, 0, stream>>>(Wg1, Wlr, WgL);
  // gate bottleneck + lr head in one GEMM: proj = x @ [Wg1 | Wlr | 0]
  k_gemm_bt2<0,0><<<dim3(1,64), 256, 0, stream>>>(xb, WgL, projt, MTOT, 128, D_);
  k_post_gl<<<MTOT/4, 256, 0, stream>>>(projt, t1b, lrb);
  // fused q|k|v projection: one N=3072 GEMM, silu on q,k, scatter to [b][h][t][e]
  k_gemm_bt2<1,2><<<dim3(24,64), 256, 0, stream>>>(xb, WqkvT, qf, MTOT, 3*D_, D_);
  // gate pre-activation into d_out (free scratch until final GEMM)
  k_gemm_bt2<0,0><<<dim3(8,64), 256, 0, stream>>>(t1b, Wg2t, out, MTOT, D_, HD_);
  k_scan8<<<256, 256, 0, stream>>>(qf, kf, vf, lrb, w1i, w3i, sob);
  k_norm_gate<<<MTOT*H_/4, 256, 0, stream>>>(sob, out, nw, yb);
  k_gemm_bt2<0,0><<<dim3(8,64), 256, 0, stream>>>(yb, Wot, out, MTOT, D_, D_);
}